// Round 17
// baseline (162.907 us; speedup 1.0000x reference)
//
#include <hip/hip_runtime.h>

#define NPTS 4096
#define NB   8
#define TOT  (2 * NB * NPTS)   // 65536 rows (dir*batch*point)
#define SCALE (-2.0f * 0.005f / 32768.f)

typedef __attribute__((ext_vector_type(8)))  short          bf16x8;
typedef __attribute__((ext_vector_type(8)))  unsigned short u16x8;
typedef __attribute__((ext_vector_type(16))) float          f32x16;

__device__ __forceinline__ unsigned short bf16_rne(float f) {
    unsigned u = __float_as_uint(f);
    u += 0x7FFFu + ((u >> 16) & 1u);
    return (unsigned short)(u >> 16);
}
__device__ __forceinline__ float bf16_f(unsigned short s) {
    return __uint_as_float(((unsigned)s) << 16);
}

// s(i,j) = ah.bh(3) + al.bh(3) + ah.bl(3) + 1*hh + 1*hl   (11 K-slots of 16)
// A slots: [ah0,ah1,ah2, al0,al1,al2, ah0,ah1 | ah2, 1, 1, 0,0,0,0,0]
// B slots: [bh0,bh1,bh2, bh0,bh1,bh2, bl0,bl1 | bl2, hh, hl, 0,0,0,0,0]
// 32x32x16 operand layout: lane l -> point (32u + (l&31)), k-slots 8*(l>>5)..+7.
// All verified on-HW R7/R9/R13/R15/R16 (absmax ~0).
// loss = SCALE * (sum_rows smax + sum_rows h_a); h_a summed in prep.

// -------- pass 0: B fragments + smax/counter init + h_a partial sums --------
__global__ __launch_bounds__(256) void prep_b(
    const float* __restrict__ x, const float* __restrict__ y,
    unsigned short* __restrict__ Bform, unsigned* __restrict__ smax,
    unsigned* __restrict__ counter, float* __restrict__ out)
{
    int i   = blockIdx.x * 256 + threadIdx.x;   // 0..65535
    int cid = i >> 12;                          // 0..7: x[b], 8..15: y[b]
    int p   = i & 4095;
    const float* src = (cid < 8) ? x + ((size_t)cid * NPTS + p) * 3
                                 : y + ((size_t)(cid - 8) * NPTS + p) * 3;
    float c0 = src[0], c1 = src[1], c2 = src[2];
    float h  = -0.5f * (c0 * c0 + c1 * c1 + c2 * c2);

    unsigned short h0 = bf16_rne(c0), h1 = bf16_rne(c1), h2 = bf16_rne(c2);
    unsigned short l0 = bf16_rne(c0 - bf16_f(h0));
    unsigned short l1 = bf16_rne(c1 - bf16_f(h1));
    unsigned short l2 = bf16_rne(c2 - bf16_f(h2));
    unsigned short hh = bf16_rne(h);
    unsigned short hl = bf16_rne(h - bf16_f(hh));

    u16x8 blo, bhi;
    blo[0]=h0; blo[1]=h1; blo[2]=h2; blo[3]=h0; blo[4]=h1; blo[5]=h2; blo[6]=l0; blo[7]=l1;
    bhi[0]=l2; bhi[1]=hh; bhi[2]=hl; bhi[3]=0; bhi[4]=0; bhi[5]=0; bhi[6]=0; bhi[7]=0;

    int u = p >> 5, pos = p & 31;
    size_t base = ((size_t)cid << 17) + (size_t)u * 1024 + (size_t)pos * 16;
    *(u16x8*)((char*)Bform + base)       = blo;
    *(u16x8*)((char*)Bform + base + 512) = bhi;

    smax[i] = 0u;        // below any order-mapped float
    if (i == 0) *counter = 0u;   // stream order: prep completes before main

    // ---- block-reduced h_a sum: one atomicAdd per block (no contention) ----
    float s = h;
    #pragma unroll
    for (int off = 32; off > 0; off >>= 1)
        s += __shfl_down(s, off);
    __shared__ float redb[4];
    const int lane = threadIdx.x & 63, wv = threadIdx.x >> 6;
    if (lane == 0) redb[wv] = s;
    __syncthreads();
    if (threadIdx.x == 0)
        atomicAdd(out, (redb[0] + redb[1] + redb[2] + redb[3]) * SCALE);
}

// -------- pass 1: MFMA chamfer core (R16 loop) + fused last-block reduce -----
// grid = 16 (dir,b) * 8 i-blocks * 4 j-quarters = 512 blocks of 256 thr
// (2 blocks/CU -> all 512 co-resident; last block to finish sums smax).
__global__ __launch_bounds__(256, 2) void chamfer_mfma(
    const float* __restrict__ x, const float* __restrict__ y,
    const unsigned short* __restrict__ Bform,
    unsigned* __restrict__ smax, unsigned* __restrict__ counter,
    float* __restrict__ out)
{
    __shared__ float buf[4][64][33];   // 33792 B, per-wave regions

    const int bid  = blockIdx.x;
    const int dirb = bid >> 5;        // 0..15 (A-cloud id)
    const int sub  = bid & 31;
    const int iblk = sub >> 2;        // 0..7
    const int jq   = sub & 3;         // 0..3

    const int tid = threadIdx.x;
    const int w   = tid >> 6;         // wave 0..3
    const int l   = tid & 63;
    const int g   = l >> 5;           // k-half
    const int pos = l & 31;           // row/col within tile

    const float* Araw = (dirb < 8) ? x + (size_t)dirb * NPTS * 3
                                   : y + (size_t)(dirb - 8) * NPTS * 3;
    const char* Bbase = (const char*)Bform + ((size_t)(dirb ^ 8) << 17);

    // ---- A fragments in-register from raw floats (R11/R15-verified) ----
    const int it0 = iblk * 16 + w * 4;
    bf16x8 afr[4];
    #pragma unroll
    for (int t = 0; t < 4; ++t) {
        const float* ap = Araw + (size_t)((it0 + t) * 32 + pos) * 3;
        float c0 = ap[0], c1 = ap[1], c2 = ap[2];
        unsigned short h0 = bf16_rne(c0), h1 = bf16_rne(c1), h2 = bf16_rne(c2);
        unsigned short l0 = bf16_rne(c0 - bf16_f(h0));
        unsigned short l1 = bf16_rne(c1 - bf16_f(h1));
        unsigned short l2 = bf16_rne(c2 - bf16_f(h2));
        const short ONE = (short)0x3F80;
        bf16x8 alo, ahi;
        alo[0]=(short)h0; alo[1]=(short)h1; alo[2]=(short)h2; alo[3]=(short)l0;
        alo[4]=(short)l1; alo[5]=(short)l2; alo[6]=(short)h0; alo[7]=(short)h1;
        ahi[0]=(short)h2; ahi[1]=ONE; ahi[2]=ONE; ahi[3]=0;
        ahi[4]=0; ahi[5]=0; ahi[6]=0; ahi[7]=0;
        #pragma unroll
        for (int e = 0; e < 8; ++e) afr[t][e] = g ? ahi[e] : alo[e];
    }

    f32x16 zc;
    #pragma unroll
    for (int r = 0; r < 16; ++r) zc[r] = 0.f;

    f32x16 run[4];
    #pragma unroll
    for (int t = 0; t < 4; ++t)
        #pragma unroll
        for (int r = 0; r < 16; ++r) run[t][r] = -3.0e38f;

    f32x16 p0, p1;
    #pragma unroll
    for (int r = 0; r < 16; ++r) { p0[r] = -3.0e38f; p1[r] = -3.0e38f; }

    const char* Bq = Bbase + (size_t)(jq * 32) * 1024
                           + (size_t)g * 512 + (size_t)pos * 16;

    bf16x8 cb0 = *(const bf16x8*)(Bq);
    bf16x8 cb1 = *(const bf16x8*)(Bq + 1024);
    bf16x8 cb2 = *(const bf16x8*)(Bq + 2048);
    bf16x8 cb3 = *(const bf16x8*)(Bq + 3072);

#define STAGE(T, B0, B1, RP)                                                    \
    {                                                                           \
        f32x16 d0 = __builtin_amdgcn_mfma_f32_32x32x16_bf16(afr[T], B0, zc, 0, 0, 0); \
        f32x16 d1 = __builtin_amdgcn_mfma_f32_32x32x16_bf16(afr[T], B1, zc, 0, 0, 0); \
        _Pragma("unroll")                                                       \
        for (int r = 0; r < 16; ++r)                                            \
            run[RP][r] = fmaxf(fmaxf(p0[r], p1[r]), run[RP][r]);                \
        p0 = d0; p1 = d1;                                                       \
    }

    #pragma unroll 1
    for (int j = 0; j < 32; j += 4) {
        bf16x8 nb0, nb1, nb2, nb3;
        if (j < 28) {                       // wave-uniform scalar branch
            const char* Bn = Bq + (size_t)(j + 4) * 1024;
            nb0 = *(const bf16x8*)(Bn);
            nb1 = *(const bf16x8*)(Bn + 1024);
            nb2 = *(const bf16x8*)(Bn + 2048);
            nb3 = *(const bf16x8*)(Bn + 3072);
        }
        STAGE(0, cb0, cb1, 3)
        STAGE(1, cb0, cb1, 0)
        STAGE(2, cb0, cb1, 1)
        STAGE(3, cb0, cb1, 2)
        STAGE(0, cb2, cb3, 3)
        STAGE(1, cb2, cb3, 0)
        STAGE(2, cb2, cb3, 1)
        STAGE(3, cb2, cb3, 2)
        if (j < 28) { cb0 = nb0; cb1 = nb1; cb2 = nb2; cb3 = nb3; }
    }
#undef STAGE

    #pragma unroll
    for (int r = 0; r < 16; ++r)
        run[3][r] = fmaxf(fmaxf(p0[r], p1[r]), run[3][r]);

    // ---- epilogue, 2 phases of 2 i-tiles each (verified R9/R13/R15/R16) ----
    #pragma unroll
    for (int ph = 0; ph < 2; ++ph) {
        if (ph) __syncthreads();
        #pragma unroll
        for (int tl = 0; tl < 2; ++tl) {
            const int t = 2 * ph + tl;
            #pragma unroll
            for (int r = 0; r < 16; ++r) {
                int rowin = (r & 3) + 8 * (r >> 2) + 4 * g;
                buf[w][tl * 32 + rowin][pos] = run[t][r];
            }
        }
        __syncthreads();

        float m = buf[w][l][0];
        #pragma unroll
        for (int k = 1; k < 32; ++k) m = fmaxf(m, buf[w][l][k]);
        int idx = dirb * 4096 + iblk * 512 + w * 128 + 2 * ph * 32 + l;
        unsigned bits = __float_as_uint(m);
        unsigned mu = (bits & 0x80000000u) ? ~bits : (bits | 0x80000000u);
        atomicMax(&smax[idx], mu);
    }

    // ---- fused reduction: last of the 512 co-resident blocks sums smax ----
    __threadfence();                       // drain this block's atomics
    __shared__ unsigned lastflag;
    if (tid == 0) lastflag = atomicAdd(counter, 1u);
    __syncthreads();
    if (lastflag == 511u) {
        float s = 0.f;
        for (int k = tid; k < TOT; k += 256) {
            // device-scope atomic read: safe across per-XCD L2s
            unsigned uv = atomicMax(&smax[k], 0u);
            unsigned bits = (uv & 0x80000000u) ? (uv & 0x7FFFFFFFu) : ~uv;
            s += __uint_as_float(bits);
        }
        #pragma unroll
        for (int off = 32; off > 0; off >>= 1)
            s += __shfl_down(s, off);
        __syncthreads();                   // buf free for reuse
        float* redb = &buf[0][0][0];
        if (l == 0) redb[w] = s;
        __syncthreads();
        if (tid == 0)
            atomicAdd(out, (redb[0] + redb[1] + redb[2] + redb[3]) * SCALE);
    }
}

extern "C" void kernel_launch(void* const* d_in, const int* in_sizes, int n_in,
                              void* d_out, int out_size, void* d_ws, size_t ws_size,
                              hipStream_t stream) {
    const float* x = (const float*)d_in[0];
    const float* y = (const float*)d_in[1];
    float* out = (float*)d_out;

    unsigned short* Bform   = (unsigned short*)d_ws;                      // 2 MB
    unsigned*       smax    = (unsigned*)((char*)d_ws + (2u << 20));      // 256 KB
    unsigned*       counter = (unsigned*)((char*)d_ws + (2u << 20) + (256u << 10));

    hipMemsetAsync(out, 0, sizeof(float), stream);
    prep_b<<<dim3(TOT / 256), dim3(256), 0, stream>>>(x, y, Bform, smax, counter, out);
    chamfer_mfma<<<dim3(512), dim3(256), 0, stream>>>(x, y, Bform, smax, counter, out);
}

// Round 18
// 70.233 us; speedup vs baseline: 2.3195x; 2.3195x over previous
//
#include <hip/hip_runtime.h>

#define NPTS 4096
#define NB   8
#define TOT  (2 * NB * NPTS)   // 65536 rows (dir*batch*point)

typedef __attribute__((ext_vector_type(8)))  short          bf16x8;
typedef __attribute__((ext_vector_type(8)))  unsigned short u16x8;
typedef __attribute__((ext_vector_type(16))) float          f32x16;

__device__ __forceinline__ unsigned short bf16_rne(float f) {
    unsigned u = __float_as_uint(f);
    u += 0x7FFFu + ((u >> 16) & 1u);
    return (unsigned short)(u >> 16);
}
__device__ __forceinline__ float bf16_f(unsigned short s) {
    return __uint_as_float(((unsigned)s) << 16);
}

// s(i,j) = ah.bh(3) + al.bh(3) + ah.bl(3) + 1*hh + 1*hl   (11 K-slots of 16)
// A slots: [ah0,ah1,ah2, al0,al1,al2, ah0,ah1 | ah2, 1, 1, 0,0,0,0,0]
// B slots: [bh0,bh1,bh2, bh0,bh1,bh2, bl0,bl1 | bl2, hh, hl, 0,0,0,0,0]
// 32x32x16 operand layout: lane l -> point (32u + (l&31)), k-slots 8*(l>>5)..+7.
// All verified on-HW R7/R9/R13/R15/R16 (absmax ~0).

// ---------------- pass 0: B fragments + smax init + out init ----------------
__global__ __launch_bounds__(256) void prep_b(
    const float* __restrict__ x, const float* __restrict__ y,
    unsigned short* __restrict__ Bform, unsigned* __restrict__ smax,
    float* __restrict__ out)
{
    int i   = blockIdx.x * 256 + threadIdx.x;   // 0..65535
    int cid = i >> 12;                          // 0..7: x[b], 8..15: y[b]
    int p   = i & 4095;
    const float* src = (cid < 8) ? x + ((size_t)cid * NPTS + p) * 3
                                 : y + ((size_t)(cid - 8) * NPTS + p) * 3;
    float c0 = src[0], c1 = src[1], c2 = src[2];
    float h  = -0.5f * (c0 * c0 + c1 * c1 + c2 * c2);

    unsigned short h0 = bf16_rne(c0), h1 = bf16_rne(c1), h2 = bf16_rne(c2);
    unsigned short l0 = bf16_rne(c0 - bf16_f(h0));
    unsigned short l1 = bf16_rne(c1 - bf16_f(h1));
    unsigned short l2 = bf16_rne(c2 - bf16_f(h2));
    unsigned short hh = bf16_rne(h);
    unsigned short hl = bf16_rne(h - bf16_f(hh));

    u16x8 blo, bhi;
    blo[0]=h0; blo[1]=h1; blo[2]=h2; blo[3]=h0; blo[4]=h1; blo[5]=h2; blo[6]=l0; blo[7]=l1;
    bhi[0]=l2; bhi[1]=hh; bhi[2]=hl; bhi[3]=0; bhi[4]=0; bhi[5]=0; bhi[6]=0; bhi[7]=0;

    int u = p >> 5, pos = p & 31;
    size_t base = ((size_t)cid << 17) + (size_t)u * 1024 + (size_t)pos * 16;
    *(u16x8*)((char*)Bform + base)       = blo;
    *(u16x8*)((char*)Bform + base + 512) = bhi;

    smax[i] = 0u;        // below any order-mapped float
    if (i == 0) *out = 0.f;
}

// ---------------- pass 1: MFMA chamfer core (R16 loop, jq split 8) ----------
// grid = 16 (dir,b) * 8 i-blocks * 8 j-eighths = 1024 blocks of 256 thr.
// VGPR=96, LDS=33.8KB -> 4 blocks/CU resident (16 waves/CU): doubles the
// wave pool hiding MFMA/VMEM latency vs R16's 512-block dispatch (2/CU).
__global__ __launch_bounds__(256, 2) void chamfer_mfma(
    const float* __restrict__ x, const float* __restrict__ y,
    const unsigned short* __restrict__ Bform,
    unsigned* __restrict__ smax)
{
    __shared__ float buf[4][64][33];   // 33792 B, per-wave regions

    const int bid  = blockIdx.x;
    const int dirb = bid >> 6;        // 0..15 (A-cloud id)
    const int sub  = bid & 63;
    const int iblk = sub >> 3;        // 0..7
    const int jq   = sub & 7;         // 0..7  (16 j-tiles each)

    const int tid = threadIdx.x;
    const int w   = tid >> 6;         // wave 0..3
    const int l   = tid & 63;
    const int g   = l >> 5;           // k-half
    const int pos = l & 31;           // row/col within tile

    const float* Araw = (dirb < 8) ? x + (size_t)dirb * NPTS * 3
                                   : y + (size_t)(dirb - 8) * NPTS * 3;
    const char* Bbase = (const char*)Bform + ((size_t)(dirb ^ 8) << 17);

    // ---- A fragments in-register from raw floats (R11/R15-verified) ----
    const int it0 = iblk * 16 + w * 4;
    bf16x8 afr[4];
    #pragma unroll
    for (int t = 0; t < 4; ++t) {
        const float* ap = Araw + (size_t)((it0 + t) * 32 + pos) * 3;
        float c0 = ap[0], c1 = ap[1], c2 = ap[2];
        unsigned short h0 = bf16_rne(c0), h1 = bf16_rne(c1), h2 = bf16_rne(c2);
        unsigned short l0 = bf16_rne(c0 - bf16_f(h0));
        unsigned short l1 = bf16_rne(c1 - bf16_f(h1));
        unsigned short l2 = bf16_rne(c2 - bf16_f(h2));
        const short ONE = (short)0x3F80;
        bf16x8 alo, ahi;
        alo[0]=(short)h0; alo[1]=(short)h1; alo[2]=(short)h2; alo[3]=(short)l0;
        alo[4]=(short)l1; alo[5]=(short)l2; alo[6]=(short)h0; alo[7]=(short)h1;
        ahi[0]=(short)h2; ahi[1]=ONE; ahi[2]=ONE; ahi[3]=0;
        ahi[4]=0; ahi[5]=0; ahi[6]=0; ahi[7]=0;
        #pragma unroll
        for (int e = 0; e < 8; ++e) afr[t][e] = g ? ahi[e] : alo[e];
    }

    f32x16 zc;
    #pragma unroll
    for (int r = 0; r < 16; ++r) zc[r] = 0.f;

    f32x16 run[4];
    #pragma unroll
    for (int t = 0; t < 4; ++t)
        #pragma unroll
        for (int r = 0; r < 16; ++r) run[t][r] = -3.0e38f;

    // pipeline registers (R16-verified deferred-consume)
    f32x16 p0, p1;
    #pragma unroll
    for (int r = 0; r < 16; ++r) { p0[r] = -3.0e38f; p1[r] = -3.0e38f; }

    const char* Bq = Bbase + (size_t)(jq * 16) * 1024
                           + (size_t)g * 512 + (size_t)pos * 16;

    bf16x8 cb0 = *(const bf16x8*)(Bq);
    bf16x8 cb1 = *(const bf16x8*)(Bq + 1024);
    bf16x8 cb2 = *(const bf16x8*)(Bq + 2048);
    bf16x8 cb3 = *(const bf16x8*)(Bq + 3072);

#define STAGE(T, B0, B1, RP)                                                    \
    {                                                                           \
        f32x16 d0 = __builtin_amdgcn_mfma_f32_32x32x16_bf16(afr[T], B0, zc, 0, 0, 0); \
        f32x16 d1 = __builtin_amdgcn_mfma_f32_32x32x16_bf16(afr[T], B1, zc, 0, 0, 0); \
        _Pragma("unroll")                                                       \
        for (int r = 0; r < 16; ++r)                                            \
            run[RP][r] = fmaxf(fmaxf(p0[r], p1[r]), run[RP][r]);                \
        p0 = d0; p1 = d1;                                                       \
    }

    #pragma unroll 1
    for (int j = 0; j < 16; j += 4) {
        bf16x8 nb0, nb1, nb2, nb3;
        if (j < 12) {                       // wave-uniform scalar branch
            const char* Bn = Bq + (size_t)(j + 4) * 1024;
            nb0 = *(const bf16x8*)(Bn);
            nb1 = *(const bf16x8*)(Bn + 1024);
            nb2 = *(const bf16x8*)(Bn + 2048);
            nb3 = *(const bf16x8*)(Bn + 3072);
        }
        STAGE(0, cb0, cb1, 3)
        STAGE(1, cb0, cb1, 0)
        STAGE(2, cb0, cb1, 1)
        STAGE(3, cb0, cb1, 2)
        STAGE(0, cb2, cb3, 3)
        STAGE(1, cb2, cb3, 0)
        STAGE(2, cb2, cb3, 1)
        STAGE(3, cb2, cb3, 2)
        if (j < 12) { cb0 = nb0; cb1 = nb1; cb2 = nb2; cb3 = nb3; }
    }
#undef STAGE

    // drain: last stage used afr[3]
    #pragma unroll
    for (int r = 0; r < 16; ++r)
        run[3][r] = fmaxf(fmaxf(p0[r], p1[r]), run[3][r]);

    // ---- epilogue, 2 phases of 2 i-tiles each (verified R9/R13/R15/R16) ----
    #pragma unroll
    for (int ph = 0; ph < 2; ++ph) {
        if (ph) __syncthreads();   // phase-0 reads done before overwrite
        #pragma unroll
        for (int tl = 0; tl < 2; ++tl) {
            const int t = 2 * ph + tl;
            #pragma unroll
            for (int r = 0; r < 16; ++r) {
                int rowin = (r & 3) + 8 * (r >> 2) + 4 * g;   // verified C/D map
                buf[w][tl * 32 + rowin][pos] = run[t][r];
            }
        }
        __syncthreads();

        float m = buf[w][l][0];
        #pragma unroll
        for (int k = 1; k < 32; ++k) m = fmaxf(m, buf[w][l][k]);
        int idx = dirb * 4096 + iblk * 512 + w * 128 + 2 * ph * 32 + l;
        unsigned bits = __float_as_uint(m);
        unsigned mu = (bits & 0x80000000u) ? ~bits : (bits | 0x80000000u);
        atomicMax(&smax[idx], mu);
    }
}

// ---------------- pass 2: unmap, add h_a from raw, sum ----------------
__global__ __launch_bounds__(256) void reduce_kernel(
    const unsigned* __restrict__ smax,
    const float* __restrict__ x, const float* __restrict__ y,
    float* __restrict__ out)
{
    const int stride = 64 * 256;
    int tid = blockIdx.x * 256 + threadIdx.x;
    float s = 0.f;
    for (int k = tid; k < TOT; k += stride) {
        unsigned u = smax[k];
        unsigned bits = (u & 0x80000000u) ? (u & 0x7FFFFFFFu) : ~u;
        int cid = k >> 12, p = k & 4095;
        const float* ap = (cid < 8) ? x + ((size_t)cid * NPTS + p) * 3
                                    : y + ((size_t)(cid - 8) * NPTS + p) * 3;
        float a0 = ap[0], a1 = ap[1], a2 = ap[2];
        s += __uint_as_float(bits) - 0.5f * (a0 * a0 + a1 * a1 + a2 * a2);
    }

    #pragma unroll
    for (int off = 32; off > 0; off >>= 1)
        s += __shfl_down(s, off);

    __shared__ float redb[4];
    const int lane = threadIdx.x & 63, wave = threadIdx.x >> 6;
    if (lane == 0) redb[wave] = s;
    __syncthreads();
    if (threadIdx.x == 0) {
        float t = redb[0] + redb[1] + redb[2] + redb[3];
        // min_d = -2*(smax + h_a); loss = 0.005 * sum / 32768
        atomicAdd(out, t * (-2.0f * 0.005f / 32768.f));
    }
}

extern "C" void kernel_launch(void* const* d_in, const int* in_sizes, int n_in,
                              void* d_out, int out_size, void* d_ws, size_t ws_size,
                              hipStream_t stream) {
    const float* x = (const float*)d_in[0];
    const float* y = (const float*)d_in[1];
    float* out = (float*)d_out;

    unsigned short* Bform = (unsigned short*)d_ws;                       // 2 MB
    unsigned*       smax  = (unsigned*)((char*)d_ws + (2u << 20));       // 256 KB

    prep_b<<<dim3(TOT / 256), dim3(256), 0, stream>>>(x, y, Bform, smax, out);
    chamfer_mfma<<<dim3(1024), dim3(256), 0, stream>>>(x, y, Bform, smax);
    reduce_kernel<<<dim3(64), dim3(256), 0, stream>>>(smax, x, y, out);
}

// Round 19
// 69.325 us; speedup vs baseline: 2.3499x; 1.0131x over previous
//
#include <hip/hip_runtime.h>

#define NPTS 4096
#define NB   8
#define TOT  (2 * NB * NPTS)   // 65536 rows (dir*batch*point)

typedef __attribute__((ext_vector_type(8)))  short          bf16x8;
typedef __attribute__((ext_vector_type(8)))  unsigned short u16x8;
typedef __attribute__((ext_vector_type(16))) float          f32x16;

__device__ __forceinline__ unsigned short bf16_rne(float f) {
    unsigned u = __float_as_uint(f);
    u += 0x7FFFu + ((u >> 16) & 1u);
    return (unsigned short)(u >> 16);
}
__device__ __forceinline__ float bf16_f(unsigned short s) {
    return __uint_as_float(((unsigned)s) << 16);
}

// s(i,j) = ah.bh(3) + al.bh(3) + ah.bl(3) + 1*hh + 1*hl   (11 K-slots of 16)
// A slots: [ah0,ah1,ah2, al0,al1,al2, ah0,ah1 | ah2, 1, 1, 0,0,0,0,0]
// B slots: [bh0,bh1,bh2, bh0,bh1,bh2, bl0,bl1 | bl2, hh, hl, 0,0,0,0,0]
// 32x32x16 operand layout: lane l -> point (32u + (l&31)), k-slots 8*(l>>5)..+7.
// All verified on-HW R7/R9/R13/R15/R16 (absmax ~0).
// R19 = exact R16 restore (session best: 69.76 us).

// ---------------- pass 0: B fragments + smax init + out init ----------------
__global__ __launch_bounds__(256) void prep_b(
    const float* __restrict__ x, const float* __restrict__ y,
    unsigned short* __restrict__ Bform, unsigned* __restrict__ smax,
    float* __restrict__ out)
{
    int i   = blockIdx.x * 256 + threadIdx.x;   // 0..65535
    int cid = i >> 12;                          // 0..7: x[b], 8..15: y[b]
    int p   = i & 4095;
    const float* src = (cid < 8) ? x + ((size_t)cid * NPTS + p) * 3
                                 : y + ((size_t)(cid - 8) * NPTS + p) * 3;
    float c0 = src[0], c1 = src[1], c2 = src[2];
    float h  = -0.5f * (c0 * c0 + c1 * c1 + c2 * c2);

    unsigned short h0 = bf16_rne(c0), h1 = bf16_rne(c1), h2 = bf16_rne(c2);
    unsigned short l0 = bf16_rne(c0 - bf16_f(h0));
    unsigned short l1 = bf16_rne(c1 - bf16_f(h1));
    unsigned short l2 = bf16_rne(c2 - bf16_f(h2));
    unsigned short hh = bf16_rne(h);
    unsigned short hl = bf16_rne(h - bf16_f(hh));

    u16x8 blo, bhi;
    blo[0]=h0; blo[1]=h1; blo[2]=h2; blo[3]=h0; blo[4]=h1; blo[5]=h2; blo[6]=l0; blo[7]=l1;
    bhi[0]=l2; bhi[1]=hh; bhi[2]=hl; bhi[3]=0; bhi[4]=0; bhi[5]=0; bhi[6]=0; bhi[7]=0;

    int u = p >> 5, pos = p & 31;
    size_t base = ((size_t)cid << 17) + (size_t)u * 1024 + (size_t)pos * 16;
    *(u16x8*)((char*)Bform + base)       = blo;
    *(u16x8*)((char*)Bform + base + 512) = bhi;

    smax[i] = 0u;        // below any order-mapped float
    if (i == 0) *out = 0.f;
}

// ---------------- pass 1: MFMA chamfer core, software-pipelined max ----------
// grid = 16 (dir,b) * 8 i-blocks * 4 j-quarters = 512 blocks of 256 thr.
__global__ __launch_bounds__(256, 2) void chamfer_mfma(
    const float* __restrict__ x, const float* __restrict__ y,
    const unsigned short* __restrict__ Bform,
    unsigned* __restrict__ smax)
{
    __shared__ float buf[4][64][33];   // 33792 B, per-wave regions

    const int bid  = blockIdx.x;
    const int dirb = bid >> 5;        // 0..15 (A-cloud id)
    const int sub  = bid & 31;
    const int iblk = sub >> 2;        // 0..7
    const int jq   = sub & 3;         // 0..3

    const int tid = threadIdx.x;
    const int w   = tid >> 6;         // wave 0..3
    const int l   = tid & 63;
    const int g   = l >> 5;           // k-half
    const int pos = l & 31;           // row/col within tile

    const float* Araw = (dirb < 8) ? x + (size_t)dirb * NPTS * 3
                                   : y + (size_t)(dirb - 8) * NPTS * 3;
    const char* Bbase = (const char*)Bform + ((size_t)(dirb ^ 8) << 17);

    // ---- A fragments in-register from raw floats (R11/R15-verified) ----
    const int it0 = iblk * 16 + w * 4;
    bf16x8 afr[4];
    #pragma unroll
    for (int t = 0; t < 4; ++t) {
        const float* ap = Araw + (size_t)((it0 + t) * 32 + pos) * 3;
        float c0 = ap[0], c1 = ap[1], c2 = ap[2];
        unsigned short h0 = bf16_rne(c0), h1 = bf16_rne(c1), h2 = bf16_rne(c2);
        unsigned short l0 = bf16_rne(c0 - bf16_f(h0));
        unsigned short l1 = bf16_rne(c1 - bf16_f(h1));
        unsigned short l2 = bf16_rne(c2 - bf16_f(h2));
        const short ONE = (short)0x3F80;
        bf16x8 alo, ahi;
        alo[0]=(short)h0; alo[1]=(short)h1; alo[2]=(short)h2; alo[3]=(short)l0;
        alo[4]=(short)l1; alo[5]=(short)l2; alo[6]=(short)h0; alo[7]=(short)h1;
        ahi[0]=(short)h2; ahi[1]=ONE; ahi[2]=ONE; ahi[3]=0;
        ahi[4]=0; ahi[5]=0; ahi[6]=0; ahi[7]=0;
        #pragma unroll
        for (int e = 0; e < 8; ++e) afr[t][e] = g ? ahi[e] : alo[e];
    }

    f32x16 zc;
    #pragma unroll
    for (int r = 0; r < 16; ++r) zc[r] = 0.f;

    f32x16 run[4];
    #pragma unroll
    for (int t = 0; t < 4; ++t)
        #pragma unroll
        for (int r = 0; r < 16; ++r) run[t][r] = -3.0e38f;

    // pipeline registers: previous stage's MFMA results (dummy-initialized;
    // first consume folds -3e38 into run[3] — harmless, run starts at -3e38)
    f32x16 p0, p1;
    #pragma unroll
    for (int r = 0; r < 16; ++r) { p0[r] = -3.0e38f; p1[r] = -3.0e38f; }

    const char* Bq = Bbase + (size_t)(jq * 32) * 1024
                           + (size_t)g * 512 + (size_t)pos * 16;

    bf16x8 cb0 = *(const bf16x8*)(Bq);
    bf16x8 cb1 = *(const bf16x8*)(Bq + 1024);
    bf16x8 cb2 = *(const bf16x8*)(Bq + 2048);
    bf16x8 cb3 = *(const bf16x8*)(Bq + 3072);

#define STAGE(T, B0, B1, RP)                                                    \
    {                                                                           \
        f32x16 d0 = __builtin_amdgcn_mfma_f32_32x32x16_bf16(afr[T], B0, zc, 0, 0, 0); \
        f32x16 d1 = __builtin_amdgcn_mfma_f32_32x32x16_bf16(afr[T], B1, zc, 0, 0, 0); \
        _Pragma("unroll")                                                       \
        for (int r = 0; r < 16; ++r)                                            \
            run[RP][r] = fmaxf(fmaxf(p0[r], p1[r]), run[RP][r]);                \
        p0 = d0; p1 = d1;                                                       \
    }

    #pragma unroll 1
    for (int j = 0; j < 32; j += 4) {
        bf16x8 nb0, nb1, nb2, nb3;
        if (j < 28) {                       // wave-uniform scalar branch
            const char* Bn = Bq + (size_t)(j + 4) * 1024;
            nb0 = *(const bf16x8*)(Bn);
            nb1 = *(const bf16x8*)(Bn + 1024);
            nb2 = *(const bf16x8*)(Bn + 2048);
            nb3 = *(const bf16x8*)(Bn + 3072);
        }
        STAGE(0, cb0, cb1, 3)
        STAGE(1, cb0, cb1, 0)
        STAGE(2, cb0, cb1, 1)
        STAGE(3, cb0, cb1, 2)
        STAGE(0, cb2, cb3, 3)
        STAGE(1, cb2, cb3, 0)
        STAGE(2, cb2, cb3, 1)
        STAGE(3, cb2, cb3, 2)
        if (j < 28) { cb0 = nb0; cb1 = nb1; cb2 = nb2; cb3 = nb3; }
    }
#undef STAGE

    // drain: last stage used afr[3]
    #pragma unroll
    for (int r = 0; r < 16; ++r)
        run[3][r] = fmaxf(fmaxf(p0[r], p1[r]), run[3][r]);

    // ---- epilogue, 2 phases of 2 i-tiles each (verified R9/R13/R15/R16) ----
    #pragma unroll
    for (int ph = 0; ph < 2; ++ph) {
        if (ph) __syncthreads();   // phase-0 reads done before overwrite
        #pragma unroll
        for (int tl = 0; tl < 2; ++tl) {
            const int t = 2 * ph + tl;
            #pragma unroll
            for (int r = 0; r < 16; ++r) {
                int rowin = (r & 3) + 8 * (r >> 2) + 4 * g;   // verified C/D map
                buf[w][tl * 32 + rowin][pos] = run[t][r];
            }
        }
        __syncthreads();

        float m = buf[w][l][0];
        #pragma unroll
        for (int k = 1; k < 32; ++k) m = fmaxf(m, buf[w][l][k]);
        int idx = dirb * 4096 + iblk * 512 + w * 128 + 2 * ph * 32 + l;
        unsigned bits = __float_as_uint(m);
        unsigned mu = (bits & 0x80000000u) ? ~bits : (bits | 0x80000000u);
        atomicMax(&smax[idx], mu);
    }
}

// ---------------- pass 2: unmap, add h_a from raw, sum ----------------
__global__ __launch_bounds__(256) void reduce_kernel(
    const unsigned* __restrict__ smax,
    const float* __restrict__ x, const float* __restrict__ y,
    float* __restrict__ out)
{
    const int stride = 64 * 256;
    int tid = blockIdx.x * 256 + threadIdx.x;
    float s = 0.f;
    for (int k = tid; k < TOT; k += stride) {
        unsigned u = smax[k];
        unsigned bits = (u & 0x80000000u) ? (u & 0x7FFFFFFFu) : ~u;
        int cid = k >> 12, p = k & 4095;
        const float* ap = (cid < 8) ? x + ((size_t)cid * NPTS + p) * 3
                                    : y + ((size_t)(cid - 8) * NPTS + p) * 3;
        float a0 = ap[0], a1 = ap[1], a2 = ap[2];
        s += __uint_as_float(bits) - 0.5f * (a0 * a0 + a1 * a1 + a2 * a2);
    }

    #pragma unroll
    for (int off = 32; off > 0; off >>= 1)
        s += __shfl_down(s, off);

    __shared__ float redb[4];
    const int lane = threadIdx.x & 63, wave = threadIdx.x >> 6;
    if (lane == 0) redb[wave] = s;
    __syncthreads();
    if (threadIdx.x == 0) {
        float t = redb[0] + redb[1] + redb[2] + redb[3];
        // min_d = -2*(smax + h_a); loss = 0.005 * sum / 32768
        atomicAdd(out, t * (-2.0f * 0.005f / 32768.f));
    }
}

extern "C" void kernel_launch(void* const* d_in, const int* in_sizes, int n_in,
                              void* d_out, int out_size, void* d_ws, size_t ws_size,
                              hipStream_t stream) {
    const float* x = (const float*)d_in[0];
    const float* y = (const float*)d_in[1];
    float* out = (float*)d_out;

    unsigned short* Bform = (unsigned short*)d_ws;                       // 2 MB
    unsigned*       smax  = (unsigned*)((char*)d_ws + (2u << 20));       // 256 KB

    prep_b<<<dim3(TOT / 256), dim3(256), 0, stream>>>(x, y, Bform, smax, out);
    chamfer_mfma<<<dim3(512), dim3(256), 0, stream>>>(x, y, Bform, smax);
    reduce_kernel<<<dim3(64), dim3(256), 0, stream>>>(smax, x, y, out);
}